// Round 9
// baseline (1104.359 us; speedup 1.0000x reference)
//
#include <hip/hip_runtime.h>
#include <math.h>

#define HIDDEN  512
#define INPUT   8
#define NUM_MIX 2
#define BATCH   64
#define SEQ     2048
#define DD      12
#define KOUT    10
#define TTILE   16
#define NTILES  (SEQ/TTILE)
#define NEV     4            /* evaluator waves (steps-parallel) */
#define BLKT    512          /* 8 waves: 4 evaluators + 4 producers */

// h-state pre-scaled by 2*log2(e): tanh(h) = 1 - 2*rcp(exp2(H)+1)
#define SCALE_F 2.8853900817779268
#define AB_F    0.09765625f   /* alpha*BASE_SCALE/HIDDEN = 50/512 */
#define TWOLN2  1.3862943611198906f  /* d tanh / dH = 2ln2*E*R^2 */

typedef float v2f __attribute__((ext_vector_type(2)));
typedef float f4v __attribute__((ext_vector_type(4)));
typedef unsigned int v2u __attribute__((ext_vector_type(2)));

__device__ __forceinline__ v2f pk_fma(v2f a, v2f b, v2f c) {
    return __builtin_elementwise_fma(a, b, c);
}

template<int CTRL>
__device__ __forceinline__ float dpp_add(float x) {
    int y = __builtin_amdgcn_update_dpp(0, __float_as_int(x), CTRL, 0xF, 0xF, true);
    return x + __int_as_float(y);
}
__device__ __forceinline__ float wave_allsum(float x) {
    x = dpp_add<0x111>(x);
    x = dpp_add<0x112>(x);
    x = dpp_add<0x114>(x);
    x = dpp_add<0x118>(x);
    x = dpp_add<0x142>(x);
    x = dpp_add<0x143>(x);
    return __int_as_float(__builtin_amdgcn_readlane(__float_as_int(x), 63));
}

// Fused dual reduction: v0 = sum64(p0), v1 = sum64(p1).
__device__ __forceinline__ void allsum2(float p0, float p1,
                                        float& v0, float& v1) {
#if __has_builtin(__builtin_amdgcn_permlane32_swap)
    v2u sw = __builtin_amdgcn_permlane32_swap(
        __float_as_uint(p0), __float_as_uint(p1), false, false);
    float z = __uint_as_float(sw.x) + __uint_as_float(sw.y);
    z = dpp_add<0x111>(z);
    z = dpp_add<0x112>(z);
    z = dpp_add<0x114>(z);
    z = dpp_add<0x118>(z);
    z = dpp_add<0x142>(z);
    v0 = __int_as_float(__builtin_amdgcn_readlane(__float_as_int(z), 31));
    v1 = __int_as_float(__builtin_amdgcn_readlane(__float_as_int(z), 63));
#else
    v0 = wave_allsum(p0);
    v1 = wave_allsum(p1);
#endif
}

__global__ __launch_bounds__(BLKT) void fsm_rnn_kernel(
    const float* __restrict__ x,          // (B, SEQ, INPUT)
    const float* __restrict__ means,      // (NUM_MIX, DD)
    const float* __restrict__ scale_tril, // (NUM_MIX, DD, DD)
    const float* __restrict__ mixw,       // (NUM_MIX,)
    const float* __restrict__ seeds,      // (4, HIDDEN, DD)
    const int*   __restrict__ cur_seeds,  // (B,)
    float*       __restrict__ out)        // (B, SEQ, KOUT)
{
    // IxP pair-layout: [dbuf][tt][q][lane][pr] holds unit h = lane + 64*(2q+pr)
    __shared__ __align__(16) float IxP[2][TTILE][4][64][2];  // 64KB
    __shared__ __align__(16) float xsB[2][TTILE*INPUT];      // 1KB
    __shared__ __align__(16) float IvL[HIDDEN][INPUT];       // 16KB (scaled)
    __shared__ float PM0[HIDDEN], PM1[HIDDEN], N0[HIDDEN], N1[HIDDEN]; // 8KB
    __shared__ __align__(16) float VG[2][TTILE][8];          // per-step v,G
    __shared__ __align__(8)  float Vfin[2][TTILE][2];        // final v per step
    __shared__ double Leff[DD*DD];
    __shared__ double meansw[DD];

    const int tid  = threadIdx.x;
    const int lane = tid & 63;
    const int wid  = tid >> 6;
    const int b    = blockIdx.x;
    const int s    = cur_seeds[b];
    const float* xb = x + (size_t)b * SEQ * INPUT;
    float* outb = out + (size_t)b * SEQ * KOUT;

    // ---- mixture weights ----
    double w0 = fmax((double)mixw[0], 1e-6);
    double w1 = fmax((double)mixw[1], 1e-6);
    double wsum = w0 + w1; w0 /= wsum; w1 /= wsum;

    // ---- weighted clamped-tril L, weighted means ----
    if (tid < DD*DD) {
        int d = tid / DD, e = tid % DD;
        double acc = 0.0;
        #pragma unroll
        for (int i = 0; i < NUM_MIX; ++i) {
            float v = scale_tril[i*DD*DD + d*DD + e];
            float c = (d > e) ? v : (d == e ? fabsf(v - 1e-12f) + 1e-12f : 0.0f);
            acc += (i == 0 ? w0 : w1) * (double)c;
        }
        Leff[tid] = acc;
    }
    if (tid < DD)
        meansw[tid] = w0 * (double)means[tid] + w1 * (double)means[DD + tid];
    if (tid < 2*TTILE*INPUT)
        ((float*)xsB)[tid] = xb[tid];          // stage x tiles 0,1
    __syncthreads();

    // ---- per-h params (double), stored pre-scaled; h = tid (512 threads) ----
    {
        const int h = tid;
        const float* sh = &seeds[(s*HIDDEN + h)*DD];
        double comb[DD];
        #pragma unroll
        for (int d = 0; d < DD; ++d) {
            double acc = meansw[d];
            for (int e = 0; e <= d; ++e)
                acc += Leff[d*DD + e] * (double)sh[e];
            comb[d] = acc;
        }
        PM0[h] = (float)(SCALE_F * (double)AB_F * comb[0]);
        PM1[h] = (float)(SCALE_F * (double)AB_F * comb[1]);
        N0[h]  = (float)comb[2];
        N1[h]  = (float)comb[3];
        #pragma unroll
        for (int i = 0; i < INPUT; ++i)
            IvL[h][i] = (float)(SCALE_F * 0.1 * comb[4 + i]);
    }
    __syncthreads();

    // ---- persistent per-role state ----
    // Within-tile split (exact): H_t = Hbase_t + AM*W_t,
    //   Hbase_{t+1} = 0.9*Hbase_t + CC_t (per-unit, parallel),
    //   W_{t+1} = 0.9*W_t + v_t (2-dim), W_{tile start} = 0,
    //   v_t = Sum_h n_h * tanh(H_t).
    // Per tile: eval all 16 steps in parallel (4 waves x 4 steps) at guessed W,
    // with Jacobian G = dv/dW; serial 2-dim linearized pass corrects; repeat once.
    v2f AM0[4], AM1[4], N0v[4], N1v[4], C00[4], C01[4], C10[4], C11[4], Hst[4];
    float vh0 = 0.f, vh1 = 0.f;     // last final v (guess seed); v_{-1}=0 exact
    f4v IvA0{}, IvC0{}, IvA1{}, IvC1{};
    float zf = 0.f, wst = 0.f;
    const int zi = lane - 56;

    if (wid < NEV) {
        #pragma unroll
        for (int q = 0; q < 4; ++q) {
            int ha = lane + 128*q, hb = ha + 64;
            AM0[q] = (v2f){PM0[ha], PM0[hb]};
            AM1[q] = (v2f){PM1[ha], PM1[hb]};
            N0v[q] = (v2f){N0[ha],  N0[hb]};
            N1v[q] = (v2f){N1[ha],  N1[hb]};
            C00[q] = N0v[q] * AM0[q];   // dv0/dWa weights (scaled-H domain)
            C01[q] = N0v[q] * AM1[q];
            C10[q] = N1v[q] * AM0[q];
            C11[q] = N1v[q] * AM1[q];
            Hst[q] = (v2f){0.0f, 0.0f};  // H_0 = 0
        }
    } else {
        const int u0 = (wid - NEV)*128 + lane;   // producer p owns q = p
        IvA0 = *(const f4v*)&IvL[u0][0];
        IvC0 = *(const f4v*)&IvL[u0][4];
        IvA1 = *(const f4v*)&IvL[u0 + 64][0];
        IvC1 = *(const f4v*)&IvL[u0 + 64][4];
    }

    // producer: fill IxP tile tg (2 units/lane); wave NEV lanes 56-63 emit z
    auto produce = [&](int tg) {
        const int pbx = tg & 1;
        const int p = wid - NEV;
        const float* xs = xsB[pbx];
        #pragma unroll
        for (int tt = 0; tt < TTILE; ++tt) {
            f4v xa = *(const f4v*)&xs[tt*INPUT];
            f4v xc = *(const f4v*)&xs[tt*INPUT + 4];
            float va = IvA0.x*xa.x;
            va = fmaf(IvA0.y, xa.y, va); va = fmaf(IvA0.z, xa.z, va);
            va = fmaf(IvA0.w, xa.w, va); va = fmaf(IvC0.x, xc.x, va);
            va = fmaf(IvC0.y, xc.y, va); va = fmaf(IvC0.z, xc.z, va);
            va = fmaf(IvC0.w, xc.w, va);
            float vb = IvA1.x*xa.x;
            vb = fmaf(IvA1.y, xa.y, vb); vb = fmaf(IvA1.z, xa.z, vb);
            vb = fmaf(IvA1.w, xa.w, vb); vb = fmaf(IvC1.x, xc.x, vb);
            vb = fmaf(IvC1.y, xc.y, vb); vb = fmaf(IvC1.z, xc.z, vb);
            vb = fmaf(IvC1.w, xc.w, vb);
            *(v2f*)&IxP[pbx][tt][p][lane][0] = (v2f){va, vb};
        }
        if (wid == NEV && lane >= 56) {
            #pragma unroll 4
            for (int tt = 0; tt < TTILE; ++tt) {
                zf = fmaf(0.9f, zf, 0.1f * xs[tt*INPUT + zi]);
                outb[(tg*TTILE + tt)*KOUT + 2 + zi] = zf;
            }
        }
    };

    // w-EMA for cols 0,1 (wave NEV, lanes 54,55) — reads Vfin of given tile
    auto process_w = [&](int tile) {
        if (lane == 54 || lane == 55) {
            const int widx = lane & 1;
            for (int tt = 0; tt < TTILE; ++tt) {
                wst = fmaf(0.9f, wst, AB_F * Vfin[tile & 1][tt][widx]);
                outb[(tile*TTILE + tt)*KOUT + widx] = wst;
            }
        }
    };

    if (wid >= NEV) produce(0);
    __syncthreads();

    for (int T = 0; T < NTILES; ++T) {
        const int pb = T & 1;
        v2f HbOwn[4][4], HbC[4];
        float WgA1[4], WgB1[4], WgA2[4], WgB2[4];
        float W16a[16], W16b[16];

        if (wid < NEV) {
            // ---- Phase A1: Hbase EMA + guess-W chain, own-step capture ----
            v2f Hb[4] = {Hst[0], Hst[1], Hst[2], Hst[3]};
            float Wa = 0.f, Wb = 0.f;
            #pragma unroll
            for (int jg = 0; jg < 4; ++jg) {
                const bool own = (jg == wid);   // wave-uniform
                #pragma unroll
                for (int ii = 0; ii < 4; ++ii) {
                    const int j = jg*4 + ii;
                    if (own) {
                        #pragma unroll
                        for (int q = 0; q < 4; ++q) HbOwn[ii][q] = Hb[q];
                        WgA1[ii] = Wa; WgB1[ii] = Wb;
                    }
                    #pragma unroll
                    for (int q = 0; q < 4; ++q) {
                        v2f cc = *(const v2f*)&IxP[pb][j][q][lane][0];
                        Hb[q] = pk_fma((v2f){0.9f, 0.9f}, Hb[q], cc);
                    }
                    Wa = fmaf(0.9f, Wa, vh0);
                    Wb = fmaf(0.9f, Wb, vh1);
                }
            }
            #pragma unroll
            for (int q = 0; q < 4; ++q) HbC[q] = Hb[q];   // Hbase carry-out

            // ---- Phase A2: eval iter1 (v + Jacobian) at guessed W ----
            #pragma unroll
            for (int i = 0; i < 4; ++i) {
                v2f gav = {WgA1[i], WgA1[i]}, gbv = {WgB1[i], WgB1[i]};
                v2f pv0, pv1, pg00, pg01, pg10, pg11;
                #pragma unroll
                for (int q = 0; q < 4; ++q) {
                    v2f Hq = pk_fma(AM0[q], gav, pk_fma(AM1[q], gbv, HbOwn[i][q]));
                    v2f E, R;
                    E.x = __builtin_amdgcn_exp2f(Hq.x);
                    E.y = __builtin_amdgcn_exp2f(Hq.y);
                    v2f A = E + 1.0f;
                    R.x = __builtin_amdgcn_rcpf(A.x);
                    R.y = __builtin_amdgcn_rcpf(A.y);
                    v2f Th = pk_fma((v2f){-2.f,-2.f}, R, (v2f){1.f,1.f});
                    v2f S2 = (E * R) * R * (v2f){TWOLN2, TWOLN2};
                    if (q == 0) {
                        pv0 = Th*N0v[0];  pv1 = Th*N1v[0];
                        pg00 = S2*C00[0]; pg01 = S2*C01[0];
                        pg10 = S2*C10[0]; pg11 = S2*C11[0];
                    } else {
                        pv0 = pk_fma(Th, N0v[q], pv0);
                        pv1 = pk_fma(Th, N1v[q], pv1);
                        pg00 = pk_fma(S2, C00[q], pg00);
                        pg01 = pk_fma(S2, C01[q], pg01);
                        pg10 = pk_fma(S2, C10[q], pg10);
                        pg11 = pk_fma(S2, C11[q], pg11);
                    }
                }
                float v0, v1, g00, g01, g10, g11;
                allsum2(pv0.x + pv0.y,  pv1.x + pv1.y,  v0,  v1);
                allsum2(pg00.x + pg00.y, pg01.x + pg01.y, g00, g01);
                allsum2(pg10.x + pg10.y, pg11.x + pg11.y, g10, g11);
                if (lane == 0) {
                    const int t = wid*4 + i;
                    *(v2f*)&VG[0][t][0] = (v2f){v0, v1};
                    *(f4v*)&VG[0][t][4] = (f4v){g00, g01, g10, g11};
                }
            }
        } else {
            if (T + 1 < NTILES) produce(T + 1);
            if (wid == NEV + 1 && T + 2 < NTILES) {
                const int base = (T + 2)*(TTILE*INPUT);
                xsB[T & 1][lane]      = xb[base + lane];
                xsB[T & 1][lane + 64] = xb[base + lane + 64];
            }
            if (wid == NEV && T >= 1) process_w(T - 1);
        }
        __syncthreads();   // B1: VG[0] complete

        if (wid < NEV) {
            // ---- pass1: serial 2-dim linearized solve (redundant per lane) ----
            float Wca = 0.f, Wcb = 0.f, Wga = 0.f, Wgb = 0.f;
            #pragma unroll
            for (int jg = 0; jg < 4; ++jg) {
                const bool own = (jg == wid);
                #pragma unroll
                for (int ii = 0; ii < 4; ++ii) {
                    const int t = jg*4 + ii;
                    f4v dv = *(const f4v*)&VG[0][t][0];
                    f4v dG = *(const f4v*)&VG[0][t][4];
                    if (own) { WgA2[ii] = Wca; WgB2[ii] = Wcb; }
                    float dA = Wca - Wga, dB = Wcb - Wgb;
                    float v0f = fmaf(dG.x, dA, fmaf(dG.y, dB, dv.x));
                    float v1f = fmaf(dG.z, dA, fmaf(dG.w, dB, dv.y));
                    W16a[t] = Wca; W16b[t] = Wcb;
                    Wga = fmaf(0.9f, Wga, vh0);
                    Wgb = fmaf(0.9f, Wgb, vh1);
                    Wca = fmaf(0.9f, Wca, v0f);
                    Wcb = fmaf(0.9f, Wcb, v1f);
                }
            }
            // ---- eval iter2 (v only; reuse iter1's G in pass2) ----
            #pragma unroll
            for (int i = 0; i < 4; ++i) {
                v2f gav = {WgA2[i], WgA2[i]}, gbv = {WgB2[i], WgB2[i]};
                v2f pv0, pv1;
                #pragma unroll
                for (int q = 0; q < 4; ++q) {
                    v2f Hq = pk_fma(AM0[q], gav, pk_fma(AM1[q], gbv, HbOwn[i][q]));
                    v2f E, R;
                    E.x = __builtin_amdgcn_exp2f(Hq.x);
                    E.y = __builtin_amdgcn_exp2f(Hq.y);
                    v2f A = E + 1.0f;
                    R.x = __builtin_amdgcn_rcpf(A.x);
                    R.y = __builtin_amdgcn_rcpf(A.y);
                    v2f Th = pk_fma((v2f){-2.f,-2.f}, R, (v2f){1.f,1.f});
                    if (q == 0) { pv0 = Th*N0v[0]; pv1 = Th*N1v[0]; }
                    else {
                        pv0 = pk_fma(Th, N0v[q], pv0);
                        pv1 = pk_fma(Th, N1v[q], pv1);
                    }
                }
                float v0, v1;
                allsum2(pv0.x + pv0.y, pv1.x + pv1.y, v0, v1);
                if (lane == 0)
                    *(v2f*)&VG[1][wid*4 + i][0] = (v2f){v0, v1};
            }
        }
        __syncthreads();   // B2: VG[1] complete

        if (wid < NEV) {
            // ---- pass2: final correction around W16; emit outputs/state ----
            float Wca = 0.f, Wcb = 0.f;
            float vl0 = 0.f, vl1 = 0.f;
            #pragma unroll
            for (int t = 0; t < TTILE; ++t) {
                f4v dv = *(const f4v*)&VG[1][t][0];
                f4v dG = *(const f4v*)&VG[0][t][4];
                float dA = Wca - W16a[t], dB = Wcb - W16b[t];
                float v0f = fmaf(dG.x, dA, fmaf(dG.y, dB, dv.x));
                float v1f = fmaf(dG.z, dA, fmaf(dG.w, dB, dv.y));
                if (tid == 0)
                    *(v2f*)&Vfin[pb][t][0] = (v2f){v0f, v1f};
                Wca = fmaf(0.9f, Wca, v0f);
                Wcb = fmaf(0.9f, Wcb, v1f);
                vl0 = v0f; vl1 = v1f;
            }
            vh0 = vl0; vh1 = vl1;                 // guess seed for next tile
            v2f wav = {Wca, Wca}, wbv = {Wcb, Wcb};
            #pragma unroll
            for (int q = 0; q < 4; ++q)           // exact H carry-out
                Hst[q] = pk_fma(AM0[q], wav, pk_fma(AM1[q], wbv, HbC[q]));
        }
        __syncthreads();   // B3: Vfin ready; IxP[1-pb] complete for next tile
    }
    if (wid == NEV) process_w(NTILES - 1);
}

extern "C" void kernel_launch(void* const* d_in, const int* in_sizes, int n_in,
                              void* d_out, int out_size, void* d_ws, size_t ws_size,
                              hipStream_t stream) {
    (void)d_ws; (void)ws_size;
    const float* x          = (const float*)d_in[0];
    const float* means      = (const float*)d_in[1];
    const float* scale_tril = (const float*)d_in[2];
    const float* mixw       = (const float*)d_in[3];
    const float* seeds      = (const float*)d_in[4];
    const int*   cur_seeds  = (const int*)d_in[5];
    float* out = (float*)d_out;

    fsm_rnn_kernel<<<BATCH, BLKT, 0, stream>>>(
        x, means, scale_tril, mixw, seeds, cur_seeds, out);
}

// Round 10
// 716.871 us; speedup vs baseline: 1.5405x; 1.5405x over previous
//
#include <hip/hip_runtime.h>
#include <math.h>

#define HIDDEN  512
#define INPUT   8
#define NUM_MIX 2
#define BATCH   64
#define SEQ     2048
#define DD      12
#define KOUT    10
#define TTILE   16
#define NTILES  (SEQ/TTILE)
#define NEV     4            /* evaluator waves (steps-parallel) */
#define BLKT    512          /* 8 waves: 4 evaluators + 4 producers */

// h-state pre-scaled by 2*log2(e): tanh(h) = 1 - 2*rcp(exp2(H)+1)
#define SCALE_F 2.8853900817779268
#define AB_F    0.09765625f   /* alpha*BASE_SCALE/HIDDEN = 50/512 */
#define TWOLN2  1.3862943611198906f  /* d tanh / dH = 2ln2*E*R^2 */

typedef float v2f __attribute__((ext_vector_type(2)));
typedef float f4v __attribute__((ext_vector_type(4)));
typedef unsigned int v2u __attribute__((ext_vector_type(2)));

__device__ __forceinline__ v2f pk_fma(v2f a, v2f b, v2f c) {
    return __builtin_elementwise_fma(a, b, c);
}

template<int CTRL>
__device__ __forceinline__ float dpp_add(float x) {
    int y = __builtin_amdgcn_update_dpp(0, __float_as_int(x), CTRL, 0xF, 0xF, true);
    return x + __int_as_float(y);
}
__device__ __forceinline__ float wave_allsum(float x) {
    x = dpp_add<0x111>(x);
    x = dpp_add<0x112>(x);
    x = dpp_add<0x114>(x);
    x = dpp_add<0x118>(x);
    x = dpp_add<0x142>(x);
    x = dpp_add<0x143>(x);
    return __int_as_float(__builtin_amdgcn_readlane(__float_as_int(x), 63));
}

// Fused dual reduction: v0 = sum64(p0), v1 = sum64(p1).
__device__ __forceinline__ void allsum2(float p0, float p1,
                                        float& v0, float& v1) {
#if __has_builtin(__builtin_amdgcn_permlane32_swap)
    v2u sw = __builtin_amdgcn_permlane32_swap(
        __float_as_uint(p0), __float_as_uint(p1), false, false);
    float z = __uint_as_float(sw.x) + __uint_as_float(sw.y);
    z = dpp_add<0x111>(z);
    z = dpp_add<0x112>(z);
    z = dpp_add<0x114>(z);
    z = dpp_add<0x118>(z);
    z = dpp_add<0x142>(z);
    v0 = __int_as_float(__builtin_amdgcn_readlane(__float_as_int(z), 31));
    v1 = __int_as_float(__builtin_amdgcn_readlane(__float_as_int(z), 63));
#else
    v0 = wave_allsum(p0);
    v1 = wave_allsum(p1);
#endif
}

__global__ __launch_bounds__(BLKT, 1) void fsm_rnn_kernel(
    const float* __restrict__ x,          // (B, SEQ, INPUT)
    const float* __restrict__ means,      // (NUM_MIX, DD)
    const float* __restrict__ scale_tril, // (NUM_MIX, DD, DD)
    const float* __restrict__ mixw,       // (NUM_MIX,)
    const float* __restrict__ seeds,      // (4, HIDDEN, DD)
    const int*   __restrict__ cur_seeds,  // (B,)
    float*       __restrict__ out)        // (B, SEQ, KOUT)
{
    // IxP pair-layout: [dbuf][tt][q][lane][pr] holds unit h = lane + 64*(2q+pr)
    __shared__ __align__(16) float IxP[2][TTILE][4][64][2];  // 64KB
    __shared__ __align__(16) float xsB[2][TTILE*INPUT];      // 1KB
    __shared__ __align__(16) float IvL[HIDDEN][INPUT];       // 16KB (scaled)
    __shared__ float PM0[HIDDEN], PM1[HIDDEN], N0[HIDDEN], N1[HIDDEN]; // 8KB
    __shared__ __align__(16) float VG[2][TTILE][8];          // per-step v,G
    __shared__ __align__(8)  float Vfin[2][TTILE][2];        // final v per step
    __shared__ __align__(8)  float Wtr[TTILE][2];            // pass1 W traj
    __shared__ double Leff[DD*DD];
    __shared__ double meansw[DD];

    const int tid  = threadIdx.x;
    const int lane = tid & 63;
    const int wid  = tid >> 6;
    const int b    = blockIdx.x;
    const int s    = cur_seeds[b];
    const float* xb = x + (size_t)b * SEQ * INPUT;
    float* outb = out + (size_t)b * SEQ * KOUT;

    // ---- mixture weights ----
    double w0 = fmax((double)mixw[0], 1e-6);
    double w1 = fmax((double)mixw[1], 1e-6);
    double wsum = w0 + w1; w0 /= wsum; w1 /= wsum;

    // ---- weighted clamped-tril L, weighted means ----
    if (tid < DD*DD) {
        int d = tid / DD, e = tid % DD;
        double acc = 0.0;
        #pragma unroll
        for (int i = 0; i < NUM_MIX; ++i) {
            float v = scale_tril[i*DD*DD + d*DD + e];
            float c = (d > e) ? v : (d == e ? fabsf(v - 1e-12f) + 1e-12f : 0.0f);
            acc += (i == 0 ? w0 : w1) * (double)c;
        }
        Leff[tid] = acc;
    }
    if (tid < DD)
        meansw[tid] = w0 * (double)means[tid] + w1 * (double)means[DD + tid];
    if (tid < 2*TTILE*INPUT)
        ((float*)xsB)[tid] = xb[tid];          // stage x tiles 0,1
    __syncthreads();

    // ---- per-h params (double), stored pre-scaled; h = tid (512 threads) ----
    {
        const int h = tid;
        const float* sh = &seeds[(s*HIDDEN + h)*DD];
        double comb[DD];
        #pragma unroll
        for (int d = 0; d < DD; ++d) {
            double acc = meansw[d];
            for (int e = 0; e <= d; ++e)
                acc += Leff[d*DD + e] * (double)sh[e];
            comb[d] = acc;
        }
        PM0[h] = (float)(SCALE_F * (double)AB_F * comb[0]);
        PM1[h] = (float)(SCALE_F * (double)AB_F * comb[1]);
        N0[h]  = (float)comb[2];
        N1[h]  = (float)comb[3];
        #pragma unroll
        for (int i = 0; i < INPUT; ++i)
            IvL[h][i] = (float)(SCALE_F * 0.1 * comb[4 + i]);
    }
    __syncthreads();

    // ---- persistent per-role state ----
    // Within-tile split (exact): H_t = Hbase_t + AM*W_t,
    //   Hbase_{t+1} = 0.9*Hbase_t + CC_t (per-unit, parallel),
    //   W_{t+1} = 0.9*W_t + v_t (2-dim), W_{tile start} = 0,
    //   v_t = Sum_h n_h * tanh(H_t).
    // Per tile: eval all 16 steps in parallel (4 waves x 4 steps) at guessed W,
    // with Jacobian G = dv/dW; serial 2-dim linearized pass corrects; repeat once.
    v2f AM0[4], AM1[4], N0v[4], N1v[4], Hst[4];
    float vh0 = 0.f, vh1 = 0.f;     // last final v (guess seed); v_{-1}=0 exact
    f4v IvA0{}, IvC0{}, IvA1{}, IvC1{};
    float zf = 0.f, wst = 0.f;
    const int zi = lane - 56;

    if (wid < NEV) {
        #pragma unroll
        for (int q = 0; q < 4; ++q) {
            int ha = lane + 128*q, hb = ha + 64;
            AM0[q] = (v2f){PM0[ha], PM0[hb]};
            AM1[q] = (v2f){PM1[ha], PM1[hb]};
            N0v[q] = (v2f){N0[ha],  N0[hb]};
            N1v[q] = (v2f){N1[ha],  N1[hb]};
            Hst[q] = (v2f){0.0f, 0.0f};  // H_0 = 0
        }
    } else {
        const int u0 = (wid - NEV)*128 + lane;   // producer p owns q = p
        IvA0 = *(const f4v*)&IvL[u0][0];
        IvC0 = *(const f4v*)&IvL[u0][4];
        IvA1 = *(const f4v*)&IvL[u0 + 64][0];
        IvC1 = *(const f4v*)&IvL[u0 + 64][4];
    }

    // producer: fill IxP tile tg (2 units/lane); wave NEV lanes 56-63 emit z
    auto produce = [&](int tg) {
        const int pbx = tg & 1;
        const int p = wid - NEV;
        const float* xs = xsB[pbx];
        #pragma unroll
        for (int tt = 0; tt < TTILE; ++tt) {
            f4v xa = *(const f4v*)&xs[tt*INPUT];
            f4v xc = *(const f4v*)&xs[tt*INPUT + 4];
            float va = IvA0.x*xa.x;
            va = fmaf(IvA0.y, xa.y, va); va = fmaf(IvA0.z, xa.z, va);
            va = fmaf(IvA0.w, xa.w, va); va = fmaf(IvC0.x, xc.x, va);
            va = fmaf(IvC0.y, xc.y, va); va = fmaf(IvC0.z, xc.z, va);
            va = fmaf(IvC0.w, xc.w, va);
            float vb = IvA1.x*xa.x;
            vb = fmaf(IvA1.y, xa.y, vb); vb = fmaf(IvA1.z, xa.z, vb);
            vb = fmaf(IvA1.w, xa.w, vb); vb = fmaf(IvC1.x, xc.x, vb);
            vb = fmaf(IvC1.y, xc.y, vb); vb = fmaf(IvC1.z, xc.z, vb);
            vb = fmaf(IvC1.w, xc.w, vb);
            *(v2f*)&IxP[pbx][tt][p][lane][0] = (v2f){va, vb};
        }
        if (wid == NEV && lane >= 56) {
            #pragma unroll 4
            for (int tt = 0; tt < TTILE; ++tt) {
                zf = fmaf(0.9f, zf, 0.1f * xs[tt*INPUT + zi]);
                outb[(tg*TTILE + tt)*KOUT + 2 + zi] = zf;
            }
        }
    };

    // w-EMA for cols 0,1 (wave NEV, lanes 54,55) — reads Vfin of given tile
    auto process_w = [&](int tile) {
        if (lane == 54 || lane == 55) {
            const int widx = lane & 1;
            for (int tt = 0; tt < TTILE; ++tt) {
                wst = fmaf(0.9f, wst, AB_F * Vfin[tile & 1][tt][widx]);
                outb[(tile*TTILE + tt)*KOUT + widx] = wst;
            }
        }
    };

    if (wid >= NEV) produce(0);
    __syncthreads();

    for (int T = 0; T < NTILES; ++T) {
        const int pb = T & 1;
        v2f HbOwn[4][4], HbC[4];
        float WgA1[4], WgB1[4], WgA2[4], WgB2[4];

        if (wid < NEV) {
            // ---- Phase A1: Hbase EMA + guess-W chain, own-step capture ----
            v2f Hb[4] = {Hst[0], Hst[1], Hst[2], Hst[3]};
            float Wa = 0.f, Wb = 0.f;
            #pragma unroll
            for (int jg = 0; jg < 4; ++jg) {
                const bool own = (jg == wid);   // wave-uniform
                #pragma unroll
                for (int ii = 0; ii < 4; ++ii) {
                    const int j = jg*4 + ii;
                    if (own) {
                        #pragma unroll
                        for (int q = 0; q < 4; ++q) HbOwn[ii][q] = Hb[q];
                        WgA1[ii] = Wa; WgB1[ii] = Wb;
                    }
                    #pragma unroll
                    for (int q = 0; q < 4; ++q) {
                        v2f cc = *(const v2f*)&IxP[pb][j][q][lane][0];
                        Hb[q] = pk_fma((v2f){0.9f, 0.9f}, Hb[q], cc);
                    }
                    Wa = fmaf(0.9f, Wa, vh0);
                    Wb = fmaf(0.9f, Wb, vh1);
                }
            }
            #pragma unroll
            for (int q = 0; q < 4; ++q) HbC[q] = Hb[q];   // Hbase carry-out

            // ---- Phase A2: eval iter1 (v + Jacobian) at guessed W ----
            #pragma unroll
            for (int i = 0; i < 4; ++i) {
                v2f gav = {WgA1[i], WgA1[i]}, gbv = {WgB1[i], WgB1[i]};
                v2f pv0, pv1, pg00, pg01, pg10, pg11;
                #pragma unroll
                for (int q = 0; q < 4; ++q) {
                    v2f Hq = pk_fma(AM0[q], gav, pk_fma(AM1[q], gbv, HbOwn[i][q]));
                    v2f E, R;
                    E.x = __builtin_amdgcn_exp2f(Hq.x);
                    E.y = __builtin_amdgcn_exp2f(Hq.y);
                    v2f A = E + 1.0f;
                    R.x = __builtin_amdgcn_rcpf(A.x);
                    R.y = __builtin_amdgcn_rcpf(A.y);
                    v2f Th = pk_fma((v2f){-2.f,-2.f}, R, (v2f){1.f,1.f});
                    v2f S2 = (E * R) * R * (v2f){TWOLN2, TWOLN2};
                    v2f t0 = S2 * AM0[q];    // on-the-fly Jacobian weights
                    v2f t1 = S2 * AM1[q];    // (saves 64 VGPR vs precompute)
                    if (q == 0) {
                        pv0 = Th*N0v[0];  pv1 = Th*N1v[0];
                        pg00 = t0*N0v[0]; pg01 = t1*N0v[0];
                        pg10 = t0*N1v[0]; pg11 = t1*N1v[0];
                    } else {
                        pv0 = pk_fma(Th, N0v[q], pv0);
                        pv1 = pk_fma(Th, N1v[q], pv1);
                        pg00 = pk_fma(t0, N0v[q], pg00);
                        pg01 = pk_fma(t1, N0v[q], pg01);
                        pg10 = pk_fma(t0, N1v[q], pg10);
                        pg11 = pk_fma(t1, N1v[q], pg11);
                    }
                }
                float v0, v1, g00, g01, g10, g11;
                allsum2(pv0.x + pv0.y,  pv1.x + pv1.y,  v0,  v1);
                allsum2(pg00.x + pg00.y, pg01.x + pg01.y, g00, g01);
                allsum2(pg10.x + pg10.y, pg11.x + pg11.y, g10, g11);
                if (lane == 0) {
                    const int t = wid*4 + i;
                    *(v2f*)&VG[0][t][0] = (v2f){v0, v1};
                    *(f4v*)&VG[0][t][4] = (f4v){g00, g01, g10, g11};
                }
            }
        } else {
            if (T + 1 < NTILES) produce(T + 1);
            if (wid == NEV + 1 && T + 2 < NTILES) {
                const int base = (T + 2)*(TTILE*INPUT);
                xsB[T & 1][lane]      = xb[base + lane];
                xsB[T & 1][lane + 64] = xb[base + lane + 64];
            }
            if (wid == NEV && T >= 1) process_w(T - 1);
        }
        __syncthreads();   // B1: VG[0] complete

        if (wid < NEV) {
            // ---- pass1: serial 2-dim linearized solve (redundant per lane) ----
            float Wca = 0.f, Wcb = 0.f, Wga = 0.f, Wgb = 0.f;
            #pragma unroll
            for (int jg = 0; jg < 4; ++jg) {
                const bool own = (jg == wid);
                #pragma unroll
                for (int ii = 0; ii < 4; ++ii) {
                    const int t = jg*4 + ii;
                    f4v dv = *(const f4v*)&VG[0][t][0];
                    f4v dG = *(const f4v*)&VG[0][t][4];
                    if (own) { WgA2[ii] = Wca; WgB2[ii] = Wcb; }
                    if (wid == 0 && lane == 0)
                        *(v2f*)&Wtr[t][0] = (v2f){Wca, Wcb};   // pass1 W traj
                    float dA = Wca - Wga, dB = Wcb - Wgb;
                    float v0f = fmaf(dG.x, dA, fmaf(dG.y, dB, dv.x));
                    float v1f = fmaf(dG.z, dA, fmaf(dG.w, dB, dv.y));
                    Wga = fmaf(0.9f, Wga, vh0);
                    Wgb = fmaf(0.9f, Wgb, vh1);
                    Wca = fmaf(0.9f, Wca, v0f);
                    Wcb = fmaf(0.9f, Wcb, v1f);
                }
            }
            // ---- eval iter2 (v only; reuse iter1's G in pass2) ----
            #pragma unroll
            for (int i = 0; i < 4; ++i) {
                v2f gav = {WgA2[i], WgA2[i]}, gbv = {WgB2[i], WgB2[i]};
                v2f pv0, pv1;
                #pragma unroll
                for (int q = 0; q < 4; ++q) {
                    v2f Hq = pk_fma(AM0[q], gav, pk_fma(AM1[q], gbv, HbOwn[i][q]));
                    v2f E, R;
                    E.x = __builtin_amdgcn_exp2f(Hq.x);
                    E.y = __builtin_amdgcn_exp2f(Hq.y);
                    v2f A = E + 1.0f;
                    R.x = __builtin_amdgcn_rcpf(A.x);
                    R.y = __builtin_amdgcn_rcpf(A.y);
                    v2f Th = pk_fma((v2f){-2.f,-2.f}, R, (v2f){1.f,1.f});
                    if (q == 0) { pv0 = Th*N0v[0]; pv1 = Th*N1v[0]; }
                    else {
                        pv0 = pk_fma(Th, N0v[q], pv0);
                        pv1 = pk_fma(Th, N1v[q], pv1);
                    }
                }
                float v0, v1;
                allsum2(pv0.x + pv0.y, pv1.x + pv1.y, v0, v1);
                if (lane == 0)
                    *(v2f*)&VG[1][wid*4 + i][0] = (v2f){v0, v1};
            }
        }
        __syncthreads();   // B2: VG[1] + Wtr complete

        if (wid < NEV) {
            // ---- pass2: final correction around Wtr; emit outputs/state ----
            float Wca = 0.f, Wcb = 0.f;
            float vl0 = 0.f, vl1 = 0.f;
            #pragma unroll
            for (int t = 0; t < TTILE; ++t) {
                f4v dv = *(const f4v*)&VG[1][t][0];
                f4v dG = *(const f4v*)&VG[0][t][4];
                v2f wr = *(const v2f*)&Wtr[t][0];
                float dA = Wca - wr.x, dB = Wcb - wr.y;
                float v0f = fmaf(dG.x, dA, fmaf(dG.y, dB, dv.x));
                float v1f = fmaf(dG.z, dA, fmaf(dG.w, dB, dv.y));
                if (tid == 0)
                    *(v2f*)&Vfin[pb][t][0] = (v2f){v0f, v1f};
                Wca = fmaf(0.9f, Wca, v0f);
                Wcb = fmaf(0.9f, Wcb, v1f);
                vl0 = v0f; vl1 = v1f;
            }
            vh0 = vl0; vh1 = vl1;                 // guess seed for next tile
            v2f wav = {Wca, Wca}, wbv = {Wcb, Wcb};
            #pragma unroll
            for (int q = 0; q < 4; ++q)           // exact H carry-out
                Hst[q] = pk_fma(AM0[q], wav, pk_fma(AM1[q], wbv, HbC[q]));
        }
        __syncthreads();   // B3: Vfin ready; IxP[1-pb] complete for next tile
    }
    if (wid == NEV) process_w(NTILES - 1);
}

extern "C" void kernel_launch(void* const* d_in, const int* in_sizes, int n_in,
                              void* d_out, int out_size, void* d_ws, size_t ws_size,
                              hipStream_t stream) {
    (void)d_ws; (void)ws_size;
    const float* x          = (const float*)d_in[0];
    const float* means      = (const float*)d_in[1];
    const float* scale_tril = (const float*)d_in[2];
    const float* mixw       = (const float*)d_in[3];
    const float* seeds      = (const float*)d_in[4];
    const int*   cur_seeds  = (const int*)d_in[5];
    float* out = (float*)d_out;

    fsm_rnn_kernel<<<BATCH, BLKT, 0, stream>>>(
        x, means, scale_tril, mixw, seeds, cur_seeds, out);
}

// Round 12
// 475.836 us; speedup vs baseline: 2.3209x; 1.5066x over previous
//
#include <hip/hip_runtime.h>
#include <math.h>

#define HIDDEN  512
#define INPUT   8
#define NUM_MIX 2
#define BATCH   64
#define SEQ     2048
#define DD      12
#define KOUT    10
#define TTILE   16
#define NTILES  (SEQ/TTILE)

// h-state kept pre-scaled by 2*log2(e): tanh(h) = 1 - 2*rcp(exp2(h_s)+1)
#define SCALE_F 2.8853900817779268
#define AB_F    0.09765625f   /* alpha*BASE_SCALE/HIDDEN = 50/512 */

typedef float v2f __attribute__((ext_vector_type(2)));
typedef float f4v __attribute__((ext_vector_type(4)));
typedef unsigned int v2u __attribute__((ext_vector_type(2)));

__device__ __forceinline__ v2f pk_fma(v2f a, v2f b, v2f c) {
    return __builtin_elementwise_fma(a, b, c);
}

template<int CTRL>
__device__ __forceinline__ float dpp_add(float x) {
    int y = __builtin_amdgcn_update_dpp(0, __float_as_int(x), CTRL, 0xF, 0xF, true);
    return x + __int_as_float(y);
}
__device__ __forceinline__ float wave_allsum(float x) {
    x = dpp_add<0x111>(x);   // row_shr:1
    x = dpp_add<0x112>(x);   // row_shr:2
    x = dpp_add<0x114>(x);   // row_shr:4
    x = dpp_add<0x118>(x);   // row_shr:8
    x = dpp_add<0x142>(x);   // row_bcast:15
    x = dpp_add<0x143>(x);   // row_bcast:31
    return __int_as_float(__builtin_amdgcn_readlane(__float_as_int(x), 63));
}

// Fused dual reduction: v0 = sum64(p0), v1 = sum64(p1).
__device__ __forceinline__ void allsum2(float p0, float p1,
                                        float& v0, float& v1) {
#if __has_builtin(__builtin_amdgcn_permlane32_swap)
    v2u sw = __builtin_amdgcn_permlane32_swap(
        __float_as_uint(p0), __float_as_uint(p1), false, false);
    float z = __uint_as_float(sw.x) + __uint_as_float(sw.y);
    z = dpp_add<0x111>(z);   // row_shr:1
    z = dpp_add<0x112>(z);   // row_shr:2
    z = dpp_add<0x114>(z);   // row_shr:4
    z = dpp_add<0x118>(z);   // row_shr:8  -> lane15/31/47/63 = row sums
    z = dpp_add<0x142>(z);   // row_bcast:15 -> lane31 = S0, lane63 = S1
    v0 = __int_as_float(__builtin_amdgcn_readlane(__float_as_int(z), 31));
    v1 = __int_as_float(__builtin_amdgcn_readlane(__float_as_int(z), 63));
#else
    v0 = wave_allsum(p0);
    v1 = wave_allsum(p1);
#endif
}

__global__ __launch_bounds__(256) void fsm_rnn_kernel(
    const float* __restrict__ x,          // (B, SEQ, INPUT)
    const float* __restrict__ means,      // (NUM_MIX, DD)
    const float* __restrict__ scale_tril, // (NUM_MIX, DD, DD)
    const float* __restrict__ mixw,       // (NUM_MIX,)
    const float* __restrict__ seeds,      // (4, HIDDEN, DD)
    const int*   __restrict__ cur_seeds,  // (B,)
    float*       __restrict__ out)        // (B, SEQ, KOUT)
{
    // IxP pair-layout: [dbuf][tt][q][lane][pr] holds unit h = lane + 64*(2q+pr)
    __shared__ __align__(16) float IxP[2][TTILE][4][64][2];  // 64KB
    __shared__ __align__(16) float xsB[2][TTILE*INPUT];      // 1KB raw x tiles
    __shared__ __align__(16) float IvL[HIDDEN][INPUT];       // 16KB alpha*I (scaled)
    __shared__ float PM0[HIDDEN], PM1[HIDDEN], N0[HIDDEN], N1[HIDDEN]; // 8KB
    __shared__ __align__(8) float vr2[2][TTILE][64][2];      // 16KB per-lane v copies
    __shared__ double Leff[DD*DD];
    __shared__ double meansw[DD];

    const int tid  = threadIdx.x;
    const int lane = tid & 63;
    const int wid  = tid >> 6;
    const int b    = blockIdx.x;
    const int s    = cur_seeds[b];
    const float* xb = x + (size_t)b * SEQ * INPUT;
    float* outb = out + (size_t)b * SEQ * KOUT;

    // ---- mixture weights ----
    double w0 = fmax((double)mixw[0], 1e-6);
    double w1 = fmax((double)mixw[1], 1e-6);
    double wsum = w0 + w1; w0 /= wsum; w1 /= wsum;

    // ---- weighted clamped-tril L, weighted means ----
    if (tid < DD*DD) {
        int d = tid / DD, e = tid % DD;
        double acc = 0.0;
        #pragma unroll
        for (int i = 0; i < NUM_MIX; ++i) {
            float v = scale_tril[i*DD*DD + d*DD + e];
            float c = (d > e) ? v : (d == e ? fabsf(v - 1e-12f) + 1e-12f : 0.0f);
            acc += (i == 0 ? w0 : w1) * (double)c;
        }
        Leff[tid] = acc;
    }
    if (tid < DD)
        meansw[tid] = w0 * (double)means[tid] + w1 * (double)means[DD + tid];
    if (tid < 2*TTILE*INPUT)
        ((float*)xsB)[tid] = xb[tid];          // stage x tiles 0,1
    __syncthreads();

    // ---- per-h params (double), stored pre-scaled ----
    #pragma unroll
    for (int rr = 0; rr < 2; ++rr) {
        int h = tid + rr*256;
        const float* sh = &seeds[(s*HIDDEN + h)*DD];
        double comb[DD];
        #pragma unroll
        for (int d = 0; d < DD; ++d) {
            double acc = meansw[d];
            for (int e = 0; e <= d; ++e)
                acc += Leff[d*DD + e] * (double)sh[e];
            comb[d] = acc;
        }
        PM0[h] = (float)(SCALE_F * (double)AB_F * comb[0]);
        PM1[h] = (float)(SCALE_F * (double)AB_F * comb[1]);
        N0[h]  = (float)comb[2];
        N1[h]  = (float)comb[3];
        #pragma unroll
        for (int i = 0; i < INPUT; ++i)
            IvL[h][i] = (float)(SCALE_F * 0.1 * comb[4 + i]);
    }
    __syncthreads();

    // ---- persistent per-role state ----
    // TH-fold: v = Sum n*(1 - 2R) = sumN + Sum (-2n)*R, R = rcp(exp2(H)+1).
    // Weights pre-scaled to -2n; sumN reduced once here.
    v2f AM0[4], AM1[4], NM0[4], NM1[4], H[4];
    float sum0 = 0.0f, sum1 = 0.0f;
    f4v IvA[3], IvC[3];
    float zf = 0.0f, wst = 0.0f;
    const int pid = (wid - 1)*64 + lane;   // producer id 0..191
    const int zi  = lane - 56;

    if (wid == 0) {
        // consumer owns h = lane + 64*m; pair q = m>>1, pr = m&1
        float ps0 = 0.0f, ps1 = 0.0f;
        #pragma unroll
        for (int q = 0; q < 4; ++q) {
            int ha = lane + 64*(2*q), hb = lane + 64*(2*q + 1);
            AM0[q] = (v2f){PM0[ha], PM0[hb]};
            AM1[q] = (v2f){PM1[ha], PM1[hb]};
            float n0a = N0[ha], n0b = N0[hb];
            float n1a = N1[ha], n1b = N1[hb];
            NM0[q] = (v2f){-2.0f*n0a, -2.0f*n0b};
            NM1[q] = (v2f){-2.0f*n1a, -2.0f*n1b};
            H[q]   = (v2f){0.0f, 0.0f};
            ps0 += n0a + n0b;
            ps1 += n1a + n1b;
        }
        allsum2(ps0, ps1, sum0, sum1);
        // priming check: H=0 -> R=0.5 -> dot = -sumN -> v = 0 exact.
    } else {
        #pragma unroll
        for (int q = 0; q < 3; ++q) {
            int h = pid + 192*q;
            if (h < HIDDEN) {
                IvA[q] = *(const f4v*)&IvL[h][0];
                IvC[q] = *(const f4v*)&IvL[h][4];
            }
        }
    }

    // producer: fill IxP tile tg; wave1 lanes 56-63 emit the z-filter outputs
    auto produce = [&](int tg) {
        const int pb = tg & 1;
        const float* xs = xsB[pb];
        for (int tt = 0; tt < TTILE; ++tt) {
            f4v xa = *(const f4v*)&xs[tt*INPUT];
            f4v xc = *(const f4v*)&xs[tt*INPUT + 4];
            #pragma unroll
            for (int q = 0; q < 3; ++q) {
                int h = pid + 192*q;
                if (h < HIDDEN) {
                    float v =      IvA[q].x * xa.x;
                    v = fmaf(IvA[q].y, xa.y, v);
                    v = fmaf(IvA[q].z, xa.z, v);
                    v = fmaf(IvA[q].w, xa.w, v);
                    v = fmaf(IvC[q].x, xc.x, v);
                    v = fmaf(IvC[q].y, xc.y, v);
                    v = fmaf(IvC[q].z, xc.z, v);
                    v = fmaf(IvC[q].w, xc.w, v);
                    IxP[pb][tt][(h >> 7)][h & 63][(h >> 6) & 1] = v;
                }
            }
        }
        if (wid == 1 && lane >= 56) {
            #pragma unroll 4
            for (int tt = 0; tt < TTILE; ++tt) {
                zf = fmaf(0.9f, zf, 0.1f * xs[tt*INPUT + zi]);
                outb[(tg*TTILE + tt)*KOUT + 2 + zi] = zf;
            }
        }
    };

    // w-EMA for cols 0,1 (wave 1, lanes 54,55) — reads lane 0's v copy
    auto process_w = [&](int tile) {
        if (lane == 54 || lane == 55) {
            const int widx = lane & 1;
            for (int tt = 0; tt < TTILE; ++tt) {
                wst = fmaf(0.9f, wst, AB_F * vr2[tile & 1][tt][0][widx]);
                outb[(tile*TTILE + tt)*KOUT + widx] = wst;
            }
        }
    };

    if (wid != 0) produce(0);
    __syncthreads();

    for (int T = 0; T < NTILES; ++T) {
        if (wid == 0) {
            const int pb = T & 1;
            v2f CC[4], CN[4];
            #pragma unroll
            for (int q = 0; q < 4; ++q)
                CC[q] = *(const v2f*)&IxP[pb][0][q][lane][0];
            #pragma unroll
            for (int tt = 0; tt < TTILE; ++tt) {
                if (tt < TTILE-1) {            // b64 prefetch, 2-way banks = free
                    #pragma unroll
                    for (int q = 0; q < 4; ++q)
                        CN[q] = *(const v2f*)&IxP[pb][tt+1][q][lane][0];
#if __has_builtin(__builtin_amdgcn_sched_group_barrier)
                    // pin the 4 ds_read_b64 at the TOP of this iteration's
                    // emitted code: a full step (~450cy) of slack hides LDS
                    // latency no matter what the scheduler's register-pressure
                    // heuristics prefer. (DS_READ mask = 0x100)
                    __builtin_amdgcn_sched_group_barrier(0x100, 4, 0);
#endif
                }
                // R = rcp(exp2(H)+1); dots directly on R with -2N weights
                v2f R[4];
                #pragma unroll
                for (int q = 0; q < 4; ++q) {
                    v2f E;
                    E.x = __builtin_amdgcn_exp2f(H[q].x);
                    E.y = __builtin_amdgcn_exp2f(H[q].y);
                    v2f A = E + 1.0f;
                    R[q].x = __builtin_amdgcn_rcpf(A.x);
                    R[q].y = __builtin_amdgcn_rcpf(A.y);
                }
                v2f s0 = R[0]*NM0[0];
                s0 = pk_fma(R[1], NM0[1], s0);
                s0 = pk_fma(R[2], NM0[2], s0);
                s0 = pk_fma(R[3], NM0[3], s0);
                v2f s1 = R[0]*NM1[0];
                s1 = pk_fma(R[1], NM1[1], s1);
                s1 = pk_fma(R[2], NM1[2], s1);
                s1 = pk_fma(R[3], NM1[3], s1);
                float p0 = s0.x + s0.y;
                float p1 = s1.x + s1.y;

                float v0p, v1p;
                allsum2(p0, p1, v0p, v1p);   // fused dual reduction
                float v0 = v0p + sum0;       // TH-fold completion
                float v1 = v1p + sum1;

                const v2f nine = {0.9f, 0.9f};
                v2f hc0 = pk_fma(nine, H[0], CC[0]);  // fills DPP shadow
                v2f hc1 = pk_fma(nine, H[1], CC[1]);
                v2f hc2 = pk_fma(nine, H[2], CC[2]);
                v2f hc3 = pk_fma(nine, H[3], CC[3]);

                v2f v0v = {v0, v0}, v1v = {v1, v1};
                H[0] = pk_fma(AM0[0], v0v, pk_fma(AM1[0], v1v, hc0));
                H[1] = pk_fma(AM0[1], v0v, pk_fma(AM1[1], v1v, hc1));
                H[2] = pk_fma(AM0[2], v0v, pk_fma(AM1[2], v1v, hc2));
                H[3] = pk_fma(AM0[3], v0v, pk_fma(AM1[3], v1v, hc3));

                // unconditional per-lane copy (identical values) — no exec games
                *(v2f*)&vr2[pb][tt][lane][0] = (v2f){v0, v1};

                #pragma unroll
                for (int q = 0; q < 4; ++q) CC[q] = CN[q];
            }
        } else {
            if (T + 1 < NTILES) produce(T + 1);
            if (wid == 2 && T + 2 < NTILES) {
                const int base = (T + 2)*(TTILE*INPUT);
                xsB[T & 1][lane]      = xb[base + lane];
                xsB[T & 1][lane + 64] = xb[base + lane + 64];
            }
            if (wid == 1 && T >= 1) process_w(T - 1);
        }
        __syncthreads();
    }
    if (wid == 1) process_w(NTILES - 1);
}

extern "C" void kernel_launch(void* const* d_in, const int* in_sizes, int n_in,
                              void* d_out, int out_size, void* d_ws, size_t ws_size,
                              hipStream_t stream) {
    (void)d_ws; (void)ws_size;
    const float* x          = (const float*)d_in[0];
    const float* means      = (const float*)d_in[1];
    const float* scale_tril = (const float*)d_in[2];
    const float* mixw       = (const float*)d_in[3];
    const float* seeds      = (const float*)d_in[4];
    const int*   cur_seeds  = (const int*)d_in[5];
    float* out = (float*)d_out;

    fsm_rnn_kernel<<<BATCH, 256, 0, stream>>>(
        x, means, scale_tril, mixw, seeds, cur_seeds, out);
}

// Round 13
// 458.642 us; speedup vs baseline: 2.4079x; 1.0375x over previous
//
#include <hip/hip_runtime.h>
#include <math.h>

#define HIDDEN  512
#define INPUT   8
#define NUM_MIX 2
#define BATCH   64
#define SEQ     2048
#define DD      12
#define KOUT    10
#define TTILE   16
#define NTILES  (SEQ/TTILE)

// h-state kept pre-scaled by 2*log2(e): tanh(h) = 1 - 2*rcp(exp2(h_s)+1)
#define SCALE_F 2.8853900817779268
#define AB_F    0.09765625f   /* alpha*BASE_SCALE/HIDDEN = 50/512 */

typedef float v2f __attribute__((ext_vector_type(2)));
typedef float f4v __attribute__((ext_vector_type(4)));
typedef unsigned int v2u __attribute__((ext_vector_type(2)));

__device__ __forceinline__ v2f pk_fma(v2f a, v2f b, v2f c) {
    return __builtin_elementwise_fma(a, b, c);
}

template<int CTRL>
__device__ __forceinline__ float dpp_add(float x) {
    int y = __builtin_amdgcn_update_dpp(0, __float_as_int(x), CTRL, 0xF, 0xF, true);
    return x + __int_as_float(y);
}
__device__ __forceinline__ float wave_allsum(float x) {
    x = dpp_add<0x111>(x);   // row_shr:1
    x = dpp_add<0x112>(x);   // row_shr:2
    x = dpp_add<0x114>(x);   // row_shr:4
    x = dpp_add<0x118>(x);   // row_shr:8
    x = dpp_add<0x142>(x);   // row_bcast:15
    x = dpp_add<0x143>(x);   // row_bcast:31
    return __int_as_float(__builtin_amdgcn_readlane(__float_as_int(x), 63));
}

// Fused dual reduction: v0 = sum64(p0), v1 = sum64(p1).
// Uses gfx950 v_permlane32_swap_b32 to fold both sums into ONE 5-level DPP
// chain: after swap+add, lanes 0-31 hold p0 pair-sums, 32-63 hold p1's.
__device__ __forceinline__ void allsum2(float p0, float p1,
                                        float& v0, float& v1) {
#if __has_builtin(__builtin_amdgcn_permlane32_swap)
    v2u sw = __builtin_amdgcn_permlane32_swap(
        __float_as_uint(p0), __float_as_uint(p1), false, false);
    float z = __uint_as_float(sw.x) + __uint_as_float(sw.y);
    z = dpp_add<0x111>(z);   // row_shr:1
    z = dpp_add<0x112>(z);   // row_shr:2
    z = dpp_add<0x114>(z);   // row_shr:4
    z = dpp_add<0x118>(z);   // row_shr:8  -> lane15/31/47/63 = row sums
    z = dpp_add<0x142>(z);   // row_bcast:15 -> lane31 = S0, lane63 = S1
    v0 = __int_as_float(__builtin_amdgcn_readlane(__float_as_int(z), 31));
    v1 = __int_as_float(__builtin_amdgcn_readlane(__float_as_int(z), 63));
#else
    v0 = wave_allsum(p0);
    v1 = wave_allsum(p1);
#endif
}

__global__ __launch_bounds__(256) void fsm_rnn_kernel(
    const float* __restrict__ x,          // (B, SEQ, INPUT)
    const float* __restrict__ means,      // (NUM_MIX, DD)
    const float* __restrict__ scale_tril, // (NUM_MIX, DD, DD)
    const float* __restrict__ mixw,       // (NUM_MIX,)
    const float* __restrict__ seeds,      // (4, HIDDEN, DD)
    const int*   __restrict__ cur_seeds,  // (B,)
    float*       __restrict__ out)        // (B, SEQ, KOUT)
{
    // IxP pair-layout: [dbuf][tt][q][lane][pr] holds unit h = lane + 64*(2q+pr)
    __shared__ __align__(16) float IxP[2][TTILE][4][64][2];  // 64KB
    __shared__ __align__(16) float xsB[2][TTILE*INPUT];      // 1KB raw x tiles
    __shared__ __align__(16) float IvL[HIDDEN][INPUT];       // 16KB alpha*I (scaled)
    __shared__ float PM0[HIDDEN], PM1[HIDDEN], N0[HIDDEN], N1[HIDDEN]; // 8KB
    __shared__ __align__(8) float vr2[2][TTILE][64][2];      // 16KB per-lane v copies
    __shared__ double Leff[DD*DD];
    __shared__ double meansw[DD];

    const int tid  = threadIdx.x;
    const int lane = tid & 63;
    const int wid  = tid >> 6;
    const int b    = blockIdx.x;
    const int s    = cur_seeds[b];
    const float* xb = x + (size_t)b * SEQ * INPUT;
    float* outb = out + (size_t)b * SEQ * KOUT;

    // ---- mixture weights ----
    double w0 = fmax((double)mixw[0], 1e-6);
    double w1 = fmax((double)mixw[1], 1e-6);
    double wsum = w0 + w1; w0 /= wsum; w1 /= wsum;

    // ---- weighted clamped-tril L, weighted means ----
    if (tid < DD*DD) {
        int d = tid / DD, e = tid % DD;
        double acc = 0.0;
        #pragma unroll
        for (int i = 0; i < NUM_MIX; ++i) {
            float v = scale_tril[i*DD*DD + d*DD + e];
            float c = (d > e) ? v : (d == e ? fabsf(v - 1e-12f) + 1e-12f : 0.0f);
            acc += (i == 0 ? w0 : w1) * (double)c;
        }
        Leff[tid] = acc;
    }
    if (tid < DD)
        meansw[tid] = w0 * (double)means[tid] + w1 * (double)means[DD + tid];
    if (tid < 2*TTILE*INPUT)
        ((float*)xsB)[tid] = xb[tid];          // stage x tiles 0,1
    __syncthreads();

    // ---- per-h params (double), stored pre-scaled ----
    #pragma unroll
    for (int rr = 0; rr < 2; ++rr) {
        int h = tid + rr*256;
        const float* sh = &seeds[(s*HIDDEN + h)*DD];
        double comb[DD];
        #pragma unroll
        for (int d = 0; d < DD; ++d) {
            double acc = meansw[d];
            for (int e = 0; e <= d; ++e)
                acc += Leff[d*DD + e] * (double)sh[e];
            comb[d] = acc;
        }
        PM0[h] = (float)(SCALE_F * (double)AB_F * comb[0]);
        PM1[h] = (float)(SCALE_F * (double)AB_F * comb[1]);
        N0[h]  = (float)comb[2];
        N1[h]  = (float)comb[3];
        #pragma unroll
        for (int i = 0; i < INPUT; ++i)
            IvL[h][i] = (float)(SCALE_F * 0.1 * comb[4 + i]);
    }
    __syncthreads();

    // ---- persistent per-role state ----
    v2f AM0[4], AM1[4], NN0v[4], NN1v[4], H[4];
    f4v IvA[3], IvC[3];
    float zf = 0.0f, wst = 0.0f;
    const int pid = (wid - 1)*64 + lane;   // producer id 0..191
    const int zi  = lane - 56;

    if (wid == 0) {
        // consumer owns h = lane + 64*m; pair q = m>>1, pr = m&1
        #pragma unroll
        for (int q = 0; q < 4; ++q) {
            int ha = lane + 64*(2*q), hb = lane + 64*(2*q + 1);
            AM0[q]  = (v2f){PM0[ha], PM0[hb]};
            AM1[q]  = (v2f){PM1[ha], PM1[hb]};
            NN0v[q] = (v2f){N0[ha],  N0[hb]};
            NN1v[q] = (v2f){N1[ha],  N1[hb]};
            H[q]    = (v2f){0.0f, 0.0f};
        }
    } else {
        #pragma unroll
        for (int q = 0; q < 3; ++q) {
            int h = pid + 192*q;
            if (h < HIDDEN) {
                IvA[q] = *(const f4v*)&IvL[h][0];
                IvC[q] = *(const f4v*)&IvL[h][4];
            }
        }
    }

    // producer: fill IxP tile tg; wave1 lanes 56-63 emit the z-filter outputs
    auto produce = [&](int tg) {
        const int pb = tg & 1;
        const float* xs = xsB[pb];
        for (int tt = 0; tt < TTILE; ++tt) {
            f4v xa = *(const f4v*)&xs[tt*INPUT];
            f4v xc = *(const f4v*)&xs[tt*INPUT + 4];
            #pragma unroll
            for (int q = 0; q < 3; ++q) {
                int h = pid + 192*q;
                if (h < HIDDEN) {
                    float v =      IvA[q].x * xa.x;
                    v = fmaf(IvA[q].y, xa.y, v);
                    v = fmaf(IvA[q].z, xa.z, v);
                    v = fmaf(IvA[q].w, xa.w, v);
                    v = fmaf(IvC[q].x, xc.x, v);
                    v = fmaf(IvC[q].y, xc.y, v);
                    v = fmaf(IvC[q].z, xc.z, v);
                    v = fmaf(IvC[q].w, xc.w, v);
                    IxP[pb][tt][(h >> 7)][h & 63][(h >> 6) & 1] = v;
                }
            }
        }
        if (wid == 1 && lane >= 56) {
            #pragma unroll 4
            for (int tt = 0; tt < TTILE; ++tt) {
                zf = fmaf(0.9f, zf, 0.1f * xs[tt*INPUT + zi]);
                outb[(tg*TTILE + tt)*KOUT + 2 + zi] = zf;
            }
        }
    };

    // w-EMA for cols 0,1 (wave 1, lanes 54,55) — reads lane 0's v copy
    auto process_w = [&](int tile) {
        if (lane == 54 || lane == 55) {
            const int widx = lane & 1;
            for (int tt = 0; tt < TTILE; ++tt) {
                wst = fmaf(0.9f, wst, AB_F * vr2[tile & 1][tt][0][widx]);
                outb[(tile*TTILE + tt)*KOUT + widx] = wst;
            }
        }
    };

    if (wid != 0) produce(0);
    __syncthreads();

    for (int T = 0; T < NTILES; ++T) {
        if (wid == 0) {
            const int pb = T & 1;
            v2f CC[4], CN[4];
            #pragma unroll
            for (int q = 0; q < 4; ++q)
                CC[q] = *(const v2f*)&IxP[pb][0][q][lane][0];
            #pragma unroll
            for (int tt = 0; tt < TTILE; ++tt) {
                if (tt < TTILE-1) {            // b64 prefetch, 2-way banks = free
                    #pragma unroll
                    for (int q = 0; q < 4; ++q)
                        CN[q] = *(const v2f*)&IxP[pb][tt+1][q][lane][0];
                }
                // tanh: scalar transcendentals, packed arithmetic (R4 numerics)
                v2f TH[4];
                #pragma unroll
                for (int q = 0; q < 4; ++q) {
                    v2f E;
                    E.x = __builtin_amdgcn_exp2f(H[q].x);
                    E.y = __builtin_amdgcn_exp2f(H[q].y);
                    v2f A = E + 1.0f;
                    v2f R;
                    R.x = __builtin_amdgcn_rcpf(A.x);
                    R.y = __builtin_amdgcn_rcpf(A.y);
                    const v2f m2 = {-2.0f, -2.0f}, one = {1.0f, 1.0f};
                    TH[q] = pk_fma(m2, R, one);
                }
                // depth-3 dot trees (same op count as depth-4 chain)
                v2f a0 = TH[0]*NN0v[0];
                a0 = pk_fma(TH[1], NN0v[1], a0);
                v2f b0 = TH[2]*NN0v[2];
                b0 = pk_fma(TH[3], NN0v[3], b0);
                v2f a1 = TH[0]*NN1v[0];
                a1 = pk_fma(TH[1], NN1v[1], a1);
                v2f b1 = TH[2]*NN1v[2];
                b1 = pk_fma(TH[3], NN1v[3], b1);
                v2f s0 = a0 + b0, s1 = a1 + b1;
                float p0 = s0.x + s0.y;
                float p1 = s1.x + s1.y;

                float v0, v1;
                allsum2(p0, p1, v0, v1);   // fused dual reduction (permlane32)

                const v2f nine = {0.9f, 0.9f};
                v2f hc0 = pk_fma(nine, H[0], CC[0]);  // fills DPP shadow
                v2f hc1 = pk_fma(nine, H[1], CC[1]);
                v2f hc2 = pk_fma(nine, H[2], CC[2]);
                v2f hc3 = pk_fma(nine, H[3], CC[3]);

                v2f v0v = {v0, v0}, v1v = {v1, v1};
                H[0] = pk_fma(AM0[0], v0v, pk_fma(AM1[0], v1v, hc0));
                H[1] = pk_fma(AM0[1], v0v, pk_fma(AM1[1], v1v, hc1));
                H[2] = pk_fma(AM0[2], v0v, pk_fma(AM1[2], v1v, hc2));
                H[3] = pk_fma(AM0[3], v0v, pk_fma(AM1[3], v1v, hc3));

                // unconditional per-lane copy (identical values) — no exec games
                *(v2f*)&vr2[pb][tt][lane][0] = (v2f){v0, v1};

                #pragma unroll
                for (int q = 0; q < 4; ++q) CC[q] = CN[q];
            }
        } else {
            if (T + 1 < NTILES) produce(T + 1);
            if (wid == 2 && T + 2 < NTILES) {
                const int base = (T + 2)*(TTILE*INPUT);
                xsB[T & 1][lane]      = xb[base + lane];
                xsB[T & 1][lane + 64] = xb[base + lane + 64];
            }
            if (wid == 1 && T >= 1) process_w(T - 1);
        }
        __syncthreads();
    }
    if (wid == 1) process_w(NTILES - 1);
}

extern "C" void kernel_launch(void* const* d_in, const int* in_sizes, int n_in,
                              void* d_out, int out_size, void* d_ws, size_t ws_size,
                              hipStream_t stream) {
    (void)d_ws; (void)ws_size;
    const float* x          = (const float*)d_in[0];
    const float* means      = (const float*)d_in[1];
    const float* scale_tril = (const float*)d_in[2];
    const float* mixw       = (const float*)d_in[3];
    const float* seeds      = (const float*)d_in[4];
    const int*   cur_seeds  = (const int*)d_in[5];
    float* out = (float*)d_out;

    fsm_rnn_kernel<<<BATCH, 256, 0, stream>>>(
        x, means, scale_tril, mixw, seeds, cur_seeds, out);
}